// Round 5
// baseline (206.857 us; speedup 1.0000x reference)
//
#include <hip/hip_runtime.h>
#include <hip/hip_bf16.h>

#define E_TOT 200000
#define NZ 64
#define ATTR_D 768
#define HID_D 128
#define NCLS 5
#define M_BLK 64        // edges per block (200000/64 = 3125 exact)
#define BKF 128         // floats staged per row per stage (512 B contiguous row visits)
#define NST 6           // 6 stages x 128 floats = 768 attr floats

typedef __attribute__((ext_vector_type(8))) short short8;   // 8 bf16 (4 VGPRs)
typedef __attribute__((ext_vector_type(4))) float f32x4;    // MFMA accumulator

typedef __attribute__((address_space(3))) unsigned       lds_u32_t;
typedef const __attribute__((address_space(1))) unsigned glob_u32_t;

__device__ __forceinline__ unsigned pk2(float a, float b) {
    __hip_bfloat162 h = __float22bfloat162_rn(make_float2(a, b));
    return *reinterpret_cast<unsigned*>(&h);
}

__device__ __forceinline__ short8 pack8(const float4 x0, const float4 x1) {
    union { unsigned u[4]; short8 s; } r;
    r.u[0] = pk2(x0.x, x0.y);
    r.u[1] = pk2(x0.z, x0.w);
    r.u[2] = pk2(x1.x, x1.y);
    r.u[3] = pk2(x1.z, x1.w);
    return r.s;
}

// ---- prep: W1 [832][128] f32 -> frag-ordered bf16 w1f[kt][f][lane][8]
// value = W1t[n = f*16 + (lane&15)][k = kt*32 + (lane>>4)*8 + j]
__global__ void prep_w1f(const float* __restrict__ W1, __hip_bfloat16* __restrict__ w1f) {
    int idx = blockIdx.x * 256 + threadIdx.x;       // over 26*8*64*8 = 106496
    if (idx >= 26 * 8 * 64 * 8) return;
    int j    = idx & 7;
    int lane = (idx >> 3) & 63;
    int f    = (idx >> 9) & 7;
    int kt   = idx >> 12;
    int n = f * 16 + (lane & 15);
    int k = kt * 32 + (lane >> 4) * 8 + j;
    w1f[idx] = __float2bfloat16(W1[(size_t)k * HID_D + n]);
}

// ---- main: 64 edges x 128 hid per block, 4 waves x 16 rows, barrier-free.
// attr staged in 512-B-per-row contiguous chunks (BK=128 f32) via global_load_lds,
// wave-local slices, 2-buffer ring. Per iteration: issue ALL B-loads (4kt x 8 frags
// -> regs) BEFORE the next stage, then one counted s_waitcnt vmcnt(8): proves
// stage s + B landed while stage s+1 (newest 8 ops) stays in flight under the MFMAs.
__global__ __launch_bounds__(256, 2) void gcn_main(
    const float* __restrict__ z, const int* __restrict__ ei,
    const float* __restrict__ attr, const __hip_bfloat16* __restrict__ w1f,
    const float* __restrict__ b1, const float* __restrict__ W2,
    const float* __restrict__ b2, float* __restrict__ out) {

    __shared__ float As[2][M_BLK * BKF];   // 2 x 32 KB

    const int t    = threadIdx.x;
    const int wv   = t >> 6;
    const int lane = t & 63;
    const int g    = lane >> 4;     // k-group
    const int c0   = lane & 15;
    const int e0   = blockIdx.x * M_BLK;

    // ---- staging sources: instruction i covers rows wv*16 + i*2 + (lane>>5),
    // physical 16B chunk p = lane&31 of the row's 512-B stage window; LDS dest is
    // linear, so the XOR swizzle (logical chunk c = p ^ (R&31)) goes on the SOURCE.
    const float* sbase[8];
#pragma unroll
    for (int i = 0; i < 8; ++i) {
        int R  = wv * 16 + i * 2 + (lane >> 5);
        int c  = (lane & 31) ^ (R & 31);
        int ec = e0 + R;
        sbase[i] = attr + (size_t)ec * ATTR_D + c * 4;
    }

    auto STAGE = [&](int buf, int s) {
#pragma unroll
        for (int i = 0; i < 8; ++i) {
            __builtin_amdgcn_global_load_lds(
                (glob_u32_t*)(sbase[i] + s * BKF),
                (lds_u32_t*)&As[buf][wv * 2048 + i * 256],
                16, 0, 0);
        }
    };

    const __hip_bfloat16* wf = w1f + (size_t)lane * 8;
    auto LOADB = [&](int kt, short8(&b)[8]) {
#pragma unroll
        for (int f = 0; f < 8; ++f)
            b[f] = *reinterpret_cast<const short8*>(wf + (size_t)(kt * 8 + f) * 512);
    };

    // ---- z-gather pointers for the k<64 phase (row = wv*16 + c0)
    const int e = e0 + wv * 16 + c0;
    const float* zsp = z + (size_t)ei[e] * NZ + g * 8;
    const float* zdp = z + (size_t)ei[E_TOT + e] * NZ + g * 8;

    f32x4 acc[8];
#pragma unroll
    for (int f = 0; f < 8; ++f) acc[f] = (f32x4){0.f, 0.f, 0.f, 0.f};

    // ---- prologue: start attr stage 0, then z-phase (its waits drain stage 0)
    STAGE(0, 0);
    {
        short8 bz0[8], bz1[8];
        LOADB(0, bz0);
        LOADB(1, bz1);
#pragma unroll
        for (int kt = 0; kt < 2; ++kt) {
            const float4* ps = reinterpret_cast<const float4*>(zsp + kt * 32);
            const float4* pd = reinterpret_cast<const float4*>(zdp + kt * 32);
            float4 s0 = ps[0], s1 = ps[1];
            float4 d0 = pd[0], d1 = pd[1];
            float4 x0 = make_float4(s0.x * d0.x, s0.y * d0.y, s0.z * d0.z, s0.w * d0.w);
            float4 x1 = make_float4(s1.x * d1.x, s1.y * d1.y, s1.z * d1.z, s1.w * d1.w);
            short8 a = pack8(x0, x1);
#pragma unroll
            for (int f = 0; f < 8; ++f) {
                short8 bb = kt ? bz1[f] : bz0[f];
                acc[f] = __builtin_amdgcn_mfma_f32_16x16x32_bf16(a, bb, acc[f], 0, 0, 0);
            }
        }
    }

    // ---- main loop: iteration s consumes buf s&1 (stage s, kt = 2+s*4 .. +3),
    // stages s+1 into buf (s+1)&1. All vm ops at the top, stage LAST.
    short8 bB[4][8];
#pragma unroll
    for (int s = 0; s < NST; ++s) {
#pragma unroll
        for (int sub = 0; sub < 4; ++sub)
            LOADB(2 + s * 4 + sub, bB[sub]);
        __builtin_amdgcn_sched_barrier(0);
        if (s < NST - 1) {
            STAGE((s + 1) & 1, s + 1);
            __builtin_amdgcn_sched_barrier(0);
            asm volatile("s_waitcnt vmcnt(8)" ::: "memory");
        } else {
            asm volatile("s_waitcnt vmcnt(0)" ::: "memory");
        }
        __builtin_amdgcn_sched_barrier(0);

        const int buf = s & 1;
        const int R31 = (wv * 16 + c0) & 31;
        const int rbase = wv * 2048 + c0 * 128;   // float index of this lane's row
#pragma unroll
        for (int sub = 0; sub < 4; ++sub) {
            int cc = sub * 8 + g * 2;
            int p0 = cc ^ R31;
            int p1 = (cc + 1) ^ R31;
            float4 x0 = *reinterpret_cast<const float4*>(&As[buf][rbase + p0 * 4]);
            float4 x1 = *reinterpret_cast<const float4*>(&As[buf][rbase + p1 * 4]);
            short8 a = pack8(x0, x1);
#pragma unroll
            for (int f = 0; f < 8; ++f)
                acc[f] = __builtin_amdgcn_mfma_f32_16x16x32_bf16(a, bB[sub][f], acc[f], 0, 0, 0);
        }
    }

    // ---- epilogue: h = relu(acc + b1); logits = h @ W2 + b2; softmax; write
    float b1v[8], w2v[8][NCLS];
#pragma unroll
    for (int f = 0; f < 8; ++f) {
        int col = f * 16 + c0;
        b1v[f] = b1[col];
#pragma unroll
        for (int cc = 0; cc < NCLS; ++cc) w2v[f][cc] = W2[col * NCLS + cc];
    }
    float b2v[NCLS];
#pragma unroll
    for (int cc = 0; cc < NCLS; ++cc) b2v[cc] = b2[cc];

#pragma unroll
    for (int i = 0; i < 4; ++i) {
        float lg[NCLS] = {0.f, 0.f, 0.f, 0.f, 0.f};
#pragma unroll
        for (int f = 0; f < 8; ++f) {
            float h = acc[f][i] + b1v[f];
            h = fmaxf(h, 0.f);
#pragma unroll
            for (int cc = 0; cc < NCLS; ++cc) lg[cc] = fmaf(h, w2v[f][cc], lg[cc]);
        }
#pragma unroll
        for (int mask = 1; mask < 16; mask <<= 1) {
#pragma unroll
            for (int cc = 0; cc < NCLS; ++cc) lg[cc] += __shfl_xor(lg[cc], mask);
        }
#pragma unroll
        for (int cc = 0; cc < NCLS; ++cc) lg[cc] += b2v[cc];

        float mx = fmaxf(fmaxf(fmaxf(lg[0], lg[1]), fmaxf(lg[2], lg[3])), lg[4]);
        float q[NCLS];
        float ssum = 0.f;
#pragma unroll
        for (int cc = 0; cc < NCLS; ++cc) { q[cc] = __expf(lg[cc] - mx); ssum += q[cc]; }
        float inv = 1.0f / ssum;
        float num = (c0 == 0) ? q[0] : (c0 == 1) ? q[1] : (c0 == 2) ? q[2]
                  : (c0 == 3) ? q[3] : q[4];
        int eo = e0 + wv * 16 + g * 4 + i;
        if (c0 < NCLS) out[(size_t)eo * NCLS + c0] = num * inv;
    }
}

extern "C" void kernel_launch(void* const* d_in, const int* in_sizes, int n_in,
                              void* d_out, int out_size, void* d_ws, size_t ws_size,
                              hipStream_t stream) {
    const float* z    = (const float*)d_in[0];
    const int*   ei   = (const int*)d_in[1];
    const float* attr = (const float*)d_in[2];
    const float* W1   = (const float*)d_in[3];
    const float* b1   = (const float*)d_in[4];
    const float* W2   = (const float*)d_in[5];
    const float* b2   = (const float*)d_in[6];
    float* out = (float*)d_out;
    __hip_bfloat16* w1f = (__hip_bfloat16*)d_ws;   // 26*8*64*8*2 = 212992 B

    prep_w1f<<<(26 * 8 * 64 * 8 + 255) / 256, 256, 0, stream>>>(W1, w1f);
    const int nblk = E_TOT / M_BLK;   // 3125 exact
    gcn_main<<<nblk, 256, 0, stream>>>(z, ei, attr, w1f, b1, W2, b2, out);
}

// Round 6
// 195.946 us; speedup vs baseline: 1.0557x; 1.0557x over previous
//
#include <hip/hip_runtime.h>
#include <hip/hip_bf16.h>

#define E_TOT 200000
#define NZ 64
#define ATTR_D 768
#define HID_D 128
#define NCLS 5
#define NSTG 12         // stages of 64 attr floats (256 B per row per stage)

typedef __attribute__((ext_vector_type(8))) short short8;   // 8 bf16 (4 VGPRs)
typedef __attribute__((ext_vector_type(4))) float f32x4;    // MFMA accumulator

typedef __attribute__((address_space(3))) unsigned       lds_u32_t;
typedef const __attribute__((address_space(1))) unsigned glob_u32_t;

__device__ __forceinline__ unsigned pk2(float a, float b) {
    __hip_bfloat162 h = __float22bfloat162_rn(make_float2(a, b));
    return *reinterpret_cast<unsigned*>(&h);
}

__device__ __forceinline__ short8 pack8(const float4 x0, const float4 x1) {
    union { unsigned u[4]; short8 s; } r;
    r.u[0] = pk2(x0.x, x0.y);
    r.u[1] = pk2(x0.z, x0.w);
    r.u[2] = pk2(x1.x, x1.y);
    r.u[3] = pk2(x1.z, x1.w);
    return r.s;
}

// ---- prep: W1 [832][128] f32 -> frag-ordered bf16 w1f[kt][f][lane][8]
// value = W1t[n = f*16 + (lane&15)][k = kt*32 + (lane>>4)*8 + j]
__global__ void prep_w1f(const float* __restrict__ W1, __hip_bfloat16* __restrict__ w1f) {
    int idx = blockIdx.x * 256 + threadIdx.x;       // over 26*8*64*8 = 106496
    if (idx >= 26 * 8 * 64 * 8) return;
    int j    = idx & 7;
    int lane = (idx >> 3) & 63;
    int f    = (idx >> 9) & 7;
    int kt   = idx >> 12;
    int n = f * 16 + (lane & 15);
    int k = kt * 32 + (lane >> 4) * 8 + j;
    w1f[idx] = __float2bfloat16(W1[(size_t)k * HID_D + n]);
}

// ---- main: 128 edges x 128 hid, 4 waves. LINEAR LDS + MONOTONIC global sources
// (no swizzle: we are HBM-bound, LDS bank conflicts are off the critical path).
// BK=64 stages, 2x32KB buffers, split sync: vmcnt(8)+s_barrier (stage s landed,
// stage s+1 in flight), lgkmcnt(0)+s_barrier (reads done), then stage s+2 into
// the buffer just read -> depth-2 pipeline with 2 buffers, no vmcnt(0) in loop.
__global__ __launch_bounds__(256, 2) void gcn_main(
    const float* __restrict__ z, const int* __restrict__ ei,
    const float* __restrict__ attr, const __hip_bfloat16* __restrict__ w1f,
    const float* __restrict__ b1, const float* __restrict__ W2,
    const float* __restrict__ b2, float* __restrict__ out) {

    __shared__ float As[2][128 * 64];   // 2 x 32 KB, row-major [row][64 floats]

    const int t    = threadIdx.x;
    const int wv   = t >> 6;
    const int lane = t & 63;
    const int g    = lane >> 4;     // k-group
    const int c0   = lane & 15;
    const int e0   = blockIdx.x * 128;

    // ---- staging sources, LINEAR: instr i covers LDS bytes [wv*1024+i*4096, +1024)
    // = 4 rows x 256 B, lanes ascending within each row's 256-B window (monotonic,
    // coalesces into 128-B line requests).
    const float* sbase[8];
#pragma unroll
    for (int i = 0; i < 8; ++i) {
        int O   = wv * 1024 + i * 4096 + lane * 16;   // byte offset in buffer
        int row = O >> 8;                              // 256 B per row
        int c   = (O >> 4) & 15;                       // 16B chunk within row window
        int er  = e0 + row; if (er >= E_TOT) er = E_TOT - 1;
        sbase[i] = attr + (size_t)er * ATTR_D + c * 4;
    }
    auto STAGE = [&](int buf, int s) {
#pragma unroll
        for (int i = 0; i < 8; ++i)
            __builtin_amdgcn_global_load_lds(
                (glob_u32_t*)(sbase[i] + s * 64),
                (lds_u32_t*)&As[buf][wv * 256 + i * 1024],
                16, 0, 0);
    };

    const __hip_bfloat16* wf = w1f + (size_t)lane * 8;
    auto LOADB = [&](int kt, short8(&b)[8]) {
#pragma unroll
        for (int f = 0; f < 8; ++f)
            b[f] = *reinterpret_cast<const short8*>(wf + (size_t)(kt * 8 + f) * 512);
    };

    f32x4 acc[2][8];
#pragma unroll
    for (int m = 0; m < 2; ++m)
#pragma unroll
        for (int f = 0; f < 8; ++f) acc[m][f] = (f32x4){0.f, 0.f, 0.f, 0.f};

    // ---- prologue. VMEM issue order matters (in-order vmcnt retirement):
    // ei, z-loads, bz, STAGE(0) | z-compute | bx, STAGE(1) | main loop.
    const float* zsp[2];
    const float* zdp[2];
#pragma unroll
    for (int m = 0; m < 2; ++m) {
        int e = e0 + wv * 32 + m * 16 + c0; if (e >= E_TOT) e = E_TOT - 1;
        zsp[m] = z + (size_t)ei[e] * NZ + g * 8;
        zdp[m] = z + (size_t)ei[E_TOT + e] * NZ + g * 8;
    }
    float4 zsr[2][2][2], zdr[2][2][2];   // [m][kt][half]
#pragma unroll
    for (int m = 0; m < 2; ++m)
#pragma unroll
        for (int kt = 0; kt < 2; ++kt)
#pragma unroll
            for (int h = 0; h < 2; ++h) {
                zsr[m][kt][h] = *reinterpret_cast<const float4*>(zsp[m] + kt * 32 + h * 4);
                zdr[m][kt][h] = *reinterpret_cast<const float4*>(zdp[m] + kt * 32 + h * 4);
            }
    short8 bz0[8], bz1[8];
    LOADB(0, bz0); LOADB(1, bz1);
    STAGE(0, 0);

#pragma unroll
    for (int kt = 0; kt < 2; ++kt) {
        short8 a[2];
#pragma unroll
        for (int m = 0; m < 2; ++m) {
            float4 x0, x1;
            x0.x = zsr[m][kt][0].x * zdr[m][kt][0].x;
            x0.y = zsr[m][kt][0].y * zdr[m][kt][0].y;
            x0.z = zsr[m][kt][0].z * zdr[m][kt][0].z;
            x0.w = zsr[m][kt][0].w * zdr[m][kt][0].w;
            x1.x = zsr[m][kt][1].x * zdr[m][kt][1].x;
            x1.y = zsr[m][kt][1].y * zdr[m][kt][1].y;
            x1.z = zsr[m][kt][1].z * zdr[m][kt][1].z;
            x1.w = zsr[m][kt][1].w * zdr[m][kt][1].w;
            a[m] = pack8(x0, x1);
        }
#pragma unroll
        for (int f = 0; f < 8; ++f) {
            short8 bb = kt ? bz1[f] : bz0[f];
            acc[0][f] = __builtin_amdgcn_mfma_f32_16x16x32_bf16(a[0], bb, acc[0][f], 0, 0, 0);
            acc[1][f] = __builtin_amdgcn_mfma_f32_16x16x32_bf16(a[1], bb, acc[1][f], 0, 0, 0);
        }
    }

    short8 bx0[8], bx1[8], by0[8], by1[8];
    LOADB(2, bx0); LOADB(3, bx1);   // B for stage 0 (kt 2,3) — before STAGE(1)
    STAGE(1, 1);

    // ---- main loop, fully unrolled. Iter S computes stage S from buf S&1.
    // Top: vmcnt(8) leaves only STAGE(S+1) in flight -> stage S + B(S) landed;
    // barrier makes it cross-wave. After reads: lgkmcnt(0)+barrier, then issue
    // B(S+1) and STAGE(S+2) into the just-read buffer.
#define ITER(S, BC0, BC1, BN0, BN1)                                            \
    {                                                                          \
        asm volatile("s_waitcnt vmcnt(8)" ::: "memory");                       \
        __builtin_amdgcn_sched_barrier(0);                                     \
        __builtin_amdgcn_s_barrier();                                          \
        float4 x[2][2][2];                                                     \
        _Pragma("unroll")                                                      \
        for (int m = 0; m < 2; ++m) {                                          \
            int r = wv * 32 + m * 16 + c0;                                     \
            _Pragma("unroll")                                                  \
            for (int kk = 0; kk < 2; ++kk) {                                   \
                const float* p = &As[(S) & 1][r * 64 + kk * 32 + g * 8];       \
                x[m][kk][0] = *reinterpret_cast<const float4*>(p);             \
                x[m][kk][1] = *reinterpret_cast<const float4*>(p + 4);         \
            }                                                                  \
        }                                                                      \
        asm volatile("s_waitcnt lgkmcnt(0)" ::: "memory");                     \
        __builtin_amdgcn_sched_barrier(0);                                     \
        __builtin_amdgcn_s_barrier();                                          \
        if ((S) + 1 < NSTG) { LOADB(2 * (S) + 4, BN0); LOADB(2 * (S) + 5, BN1); } \
        if ((S) + 2 < NSTG) STAGE((S) & 1, (S) + 2);                           \
        __builtin_amdgcn_sched_barrier(0);                                     \
        _Pragma("unroll")                                                      \
        for (int kk = 0; kk < 2; ++kk) {                                       \
            short8 a0 = pack8(x[0][kk][0], x[0][kk][1]);                       \
            short8 a1 = pack8(x[1][kk][0], x[1][kk][1]);                       \
            _Pragma("unroll")                                                  \
            for (int f = 0; f < 8; ++f) {                                      \
                short8 bb = kk ? (BC1)[f] : (BC0)[f];                          \
                acc[0][f] = __builtin_amdgcn_mfma_f32_16x16x32_bf16(a0, bb, acc[0][f], 0, 0, 0); \
                acc[1][f] = __builtin_amdgcn_mfma_f32_16x16x32_bf16(a1, bb, acc[1][f], 0, 0, 0); \
            }                                                                  \
        }                                                                      \
    }

    ITER(0,  bx0, bx1, by0, by1)
    ITER(1,  by0, by1, bx0, bx1)
    ITER(2,  bx0, bx1, by0, by1)
    ITER(3,  by0, by1, bx0, bx1)
    ITER(4,  bx0, bx1, by0, by1)
    ITER(5,  by0, by1, bx0, bx1)
    ITER(6,  bx0, bx1, by0, by1)
    ITER(7,  by0, by1, bx0, bx1)
    ITER(8,  bx0, bx1, by0, by1)
    ITER(9,  by0, by1, bx0, bx1)
    ITER(10, bx0, bx1, by0, by1)
    ITER(11, by0, by1, bx0, bx1)
#undef ITER

    // ---- epilogue: h = relu(acc + b1); logits = h @ W2 + b2; softmax; write
    float b1v[8], w2v[8][NCLS];
#pragma unroll
    for (int f = 0; f < 8; ++f) {
        int col = f * 16 + c0;
        b1v[f] = b1[col];
#pragma unroll
        for (int cc = 0; cc < NCLS; ++cc) w2v[f][cc] = W2[col * NCLS + cc];
    }
    float b2v[NCLS];
#pragma unroll
    for (int cc = 0; cc < NCLS; ++cc) b2v[cc] = b2[cc];

#pragma unroll
    for (int m = 0; m < 2; ++m) {
#pragma unroll
        for (int i = 0; i < 4; ++i) {
            float lg[NCLS] = {0.f, 0.f, 0.f, 0.f, 0.f};
#pragma unroll
            for (int f = 0; f < 8; ++f) {
                float h = acc[m][f][i] + b1v[f];
                h = fmaxf(h, 0.f);
#pragma unroll
                for (int cc = 0; cc < NCLS; ++cc) lg[cc] = fmaf(h, w2v[f][cc], lg[cc]);
            }
#pragma unroll
            for (int mask = 1; mask < 16; mask <<= 1) {
#pragma unroll
                for (int cc = 0; cc < NCLS; ++cc) lg[cc] += __shfl_xor(lg[cc], mask);
            }
#pragma unroll
            for (int cc = 0; cc < NCLS; ++cc) lg[cc] += b2v[cc];

            float mx = fmaxf(fmaxf(fmaxf(lg[0], lg[1]), fmaxf(lg[2], lg[3])), lg[4]);
            float q[NCLS];
            float s = 0.f;
#pragma unroll
            for (int cc = 0; cc < NCLS; ++cc) { q[cc] = __expf(lg[cc] - mx); s += q[cc]; }
            float inv = 1.0f / s;
            float num = (c0 == 0) ? q[0] : (c0 == 1) ? q[1] : (c0 == 2) ? q[2]
                      : (c0 == 3) ? q[3] : q[4];
            int eo = e0 + wv * 32 + m * 16 + g * 4 + i;
            if (eo < E_TOT && c0 < NCLS) out[(size_t)eo * NCLS + c0] = num * inv;
        }
    }
}

extern "C" void kernel_launch(void* const* d_in, const int* in_sizes, int n_in,
                              void* d_out, int out_size, void* d_ws, size_t ws_size,
                              hipStream_t stream) {
    const float* z    = (const float*)d_in[0];
    const int*   ei   = (const int*)d_in[1];
    const float* attr = (const float*)d_in[2];
    const float* W1   = (const float*)d_in[3];
    const float* b1   = (const float*)d_in[4];
    const float* W2   = (const float*)d_in[5];
    const float* b2   = (const float*)d_in[6];
    float* out = (float*)d_out;
    __hip_bfloat16* w1f = (__hip_bfloat16*)d_ws;   // 26*8*64*8*2 = 212992 B

    prep_w1f<<<(26 * 8 * 64 * 8 + 255) / 256, 256, 0, stream>>>(W1, w1f);
    const int nblk = (E_TOT + 127) / 128;   // 1563
    gcn_main<<<nblk, 256, 0, stream>>>(z, ei, attr, w1f, b1, W2, b2, out);
}

// Round 8
// 183.139 us; speedup vs baseline: 1.1295x; 1.0699x over previous
//
#include <hip/hip_runtime.h>
#include <hip/hip_bf16.h>

#define E_TOT 200000
#define NZ 64
#define ATTR_D 768
#define HID_D 128
#define NCLS 5

typedef __attribute__((ext_vector_type(8))) short short8;   // 8 bf16 (4 VGPRs)
typedef __attribute__((ext_vector_type(4))) float f32x4;    // MFMA accumulator

typedef __attribute__((address_space(3))) unsigned       lds_u32_t;
typedef const __attribute__((address_space(1))) unsigned glob_u32_t;

__device__ __forceinline__ unsigned pk2(float a, float b) {
    __hip_bfloat162 h = __float22bfloat162_rn(make_float2(a, b));
    return *reinterpret_cast<unsigned*>(&h);
}

__device__ __forceinline__ short8 pack8(const float4 x0, const float4 x1) {
    union { unsigned u[4]; short8 s; } r;
    r.u[0] = pk2(x0.x, x0.y);
    r.u[1] = pk2(x0.z, x0.w);
    r.u[2] = pk2(x1.x, x1.y);
    r.u[3] = pk2(x1.z, x1.w);
    return r.s;
}

// ---- prep: W1 [832][128] f32 -> frag-ordered bf16 w1f[kt][f][lane][8]
__global__ void prep_w1f(const float* __restrict__ W1, __hip_bfloat16* __restrict__ w1f) {
    int idx = blockIdx.x * 256 + threadIdx.x;       // 26*8*64*8 = 106496
    if (idx >= 26 * 8 * 64 * 8) return;
    int j    = idx & 7;
    int lane = (idx >> 3) & 63;
    int f    = (idx >> 9) & 7;
    int kt   = idx >> 12;
    int n = f * 16 + (lane & 15);
    int k = kt * 32 + (lane >> 4) * 8 + j;
    w1f[idx] = __float2bfloat16(W1[(size_t)k * HID_D + n]);
}

// ---- main: fully wave-independent, barrier-free, 2-ahead LDS ring.
// 128 edges/block, 4 waves x 32 rows. Per-iter VMEM order is pinned so that
// in-order vmcnt retirement keeps 2 stages (8 KB/wave, 64 KB/CU) in flight:
//   [vmcnt(12)] STAGE(s+3) | ds_read+MFMA(B_s) | LOADB(B_{s+2})
// newer-than-B_s = S_{s+2}(4) + B_{s+1}(8) = 12.
// Stage offset is FOLDED INTO THE GLOBAL POINTER (offset imm = 0): the builtin's
// offset-immediate semantics are unverified for LDS-DMA (R7 failure) — R3..R6,
// which passed, all fold the offset.
__global__ __launch_bounds__(256, 2) void gcn_main(
    const float* __restrict__ z, const int* __restrict__ ei,
    const float* __restrict__ attr, const __hip_bfloat16* __restrict__ w1f,
    const float* __restrict__ b1, const float* __restrict__ W2,
    const float* __restrict__ b2, float* __restrict__ out) {

    __shared__ float As[4][4096];   // 4 bufs x (4 waves x 32 rows x 32 f32) = 64 KB

    const int t    = threadIdx.x;
    const int wv   = t >> 6;
    const int lane = t & 63;
    const int g    = lane >> 4;     // k-group
    const int c0   = lane & 15;
    const int e0   = blockIdx.x * 128;

    // ---- staging sources (wave-local 32 rows). Lane covers slice-local row
    // rsl = i*8 + (lane>>3), physical 16B chunk lane&7. LDS dest linear; the
    // chunk swizzle (logical = physical ^ (row&7)) goes on the GLOBAL source —
    // a permutation WITHIN each 128B line, so line-coalescing is preserved.
    const float* sbase[4];
#pragma unroll
    for (int i = 0; i < 4; ++i) {
        int rsl = i * 8 + (lane >> 3);
        int cch = (lane & 7) ^ (rsl & 7);
        int er  = e0 + wv * 32 + rsl; if (er >= E_TOT) er = E_TOT - 1;
        sbase[i] = attr + (size_t)er * ATTR_D + cch * 4;
    }

#define SB __builtin_amdgcn_sched_barrier(0)
#define WAITVM(N) asm volatile("s_waitcnt vmcnt(" #N ")" ::: "memory")
#define STAGE(BUF, S)                                                          \
    {                                                                          \
        _Pragma("unroll")                                                      \
        for (int i = 0; i < 4; ++i)                                            \
            __builtin_amdgcn_global_load_lds(                                  \
                (glob_u32_t*)(sbase[i] + (S) * 32),                            \
                (lds_u32_t*)&As[BUF][wv * 1024 + i * 256],                     \
                16, 0, 0);                                                     \
    }

    const __hip_bfloat16* wf = w1f + (size_t)lane * 8;
    auto LOADB = [&](int kt, short8(&b)[8]) {
#pragma unroll
        for (int f = 0; f < 8; ++f)
            b[f] = *reinterpret_cast<const short8*>(wf + (size_t)(kt * 8 + f) * 512);
    };

    // ---- prologue VMEM order (pinned): ei+z | bz | S0 | S1 | B0 | S2 | B1
    const float* zsp[2];
    const float* zdp[2];
#pragma unroll
    for (int m = 0; m < 2; ++m) {
        int e = e0 + wv * 32 + m * 16 + c0; if (e >= E_TOT) e = E_TOT - 1;
        zsp[m] = z + (size_t)ei[e] * NZ + g * 8;
        zdp[m] = z + (size_t)ei[E_TOT + e] * NZ + g * 8;
    }
    float4 zsr[2][2][2], zdr[2][2][2];
#pragma unroll
    for (int m = 0; m < 2; ++m)
#pragma unroll
        for (int kt = 0; kt < 2; ++kt)
#pragma unroll
            for (int h = 0; h < 2; ++h) {
                zsr[m][kt][h] = *reinterpret_cast<const float4*>(zsp[m] + kt * 32 + h * 4);
                zdr[m][kt][h] = *reinterpret_cast<const float4*>(zdp[m] + kt * 32 + h * 4);
            }
    SB;
    short8 bz0[8], bz1[8];
    LOADB(0, bz0); LOADB(1, bz1);
    SB;
    STAGE(0, 0); SB;
    STAGE(1, 1); SB;
    short8 bX[8], bY[8];
    LOADB(2, bX);   // B_0
    SB;
    STAGE(2, 2); SB;
    LOADB(3, bY);   // B_1
    SB;

    f32x4 acc[2][8];
#pragma unroll
    for (int m = 0; m < 2; ++m)
#pragma unroll
        for (int f = 0; f < 8; ++f) acc[m][f] = (f32x4){0.f, 0.f, 0.f, 0.f};

    // ---- z-phase (kt 0,1): compiler inserts the (counted) waits for z/bz.
#pragma unroll
    for (int kt = 0; kt < 2; ++kt) {
        short8 a[2];
#pragma unroll
        for (int m = 0; m < 2; ++m) {
            float4 x0, x1;
            x0.x = zsr[m][kt][0].x * zdr[m][kt][0].x;
            x0.y = zsr[m][kt][0].y * zdr[m][kt][0].y;
            x0.z = zsr[m][kt][0].z * zdr[m][kt][0].z;
            x0.w = zsr[m][kt][0].w * zdr[m][kt][0].w;
            x1.x = zsr[m][kt][1].x * zdr[m][kt][1].x;
            x1.y = zsr[m][kt][1].y * zdr[m][kt][1].y;
            x1.z = zsr[m][kt][1].z * zdr[m][kt][1].z;
            x1.w = zsr[m][kt][1].w * zdr[m][kt][1].w;
            a[m] = pack8(x0, x1);
        }
#pragma unroll
        for (int f = 0; f < 8; ++f) {
            short8 bb = kt ? bz1[f] : bz0[f];
            acc[0][f] = __builtin_amdgcn_mfma_f32_16x16x32_bf16(a[0], bb, acc[0][f], 0, 0, 0);
            acc[1][f] = __builtin_amdgcn_mfma_f32_16x16x32_bf16(a[1], bb, acc[1][f], 0, 0, 0);
        }
    }

    // ---- main loop, 24 iters fully unrolled. Iter s: consume stage s (kt=s+2)
    // from buf s&3 with B-set (s even -> bX, odd -> bY).
#define ITER_BODY(S, BC)                                                       \
        const float* sl = &As[(S) & 3][wv * 1024];                             \
        int pA = (2 * g) ^ (c0 & 7);                                           \
        int pB = pA ^ 1;                                                       \
        float4 x00 = *reinterpret_cast<const float4*>(sl + c0 * 32 + pA * 4);  \
        float4 x01 = *reinterpret_cast<const float4*>(sl + c0 * 32 + pB * 4);  \
        float4 x10 = *reinterpret_cast<const float4*>(sl + (c0 + 16) * 32 + pA * 4); \
        float4 x11 = *reinterpret_cast<const float4*>(sl + (c0 + 16) * 32 + pB * 4); \
        short8 a0 = pack8(x00, x01);                                           \
        short8 a1 = pack8(x10, x11);                                           \
        _Pragma("unroll")                                                      \
        for (int f = 0; f < 8; ++f) {                                          \
            acc[0][f] = __builtin_amdgcn_mfma_f32_16x16x32_bf16(a0, (BC)[f], acc[0][f], 0, 0, 0); \
            acc[1][f] = __builtin_amdgcn_mfma_f32_16x16x32_bf16(a1, (BC)[f], acc[1][f], 0, 0, 0); \
        }

#define ITER_FULL(S, BC)                                                       \
    {                                                                          \
        WAITVM(12); SB;                                                        \
        STAGE(((S) + 3) & 3, (S) + 3); SB;                                     \
        ITER_BODY(S, BC)                                                       \
        SB; LOADB((S) + 4, BC); SB;                                            \
    }
#define ITER_NOS(S, BC)                                                        \
    {                                                                          \
        WAITVM(12); SB;                                                        \
        ITER_BODY(S, BC)                                                       \
        SB; LOADB((S) + 4, BC); SB;                                            \
    }
#define ITER_BARE(S, W, BC)                                                    \
    {                                                                          \
        WAITVM(W); SB;                                                         \
        ITER_BODY(S, BC)                                                       \
    }

    ITER_FULL(0,  bX) ITER_FULL(1,  bY) ITER_FULL(2,  bX) ITER_FULL(3,  bY)
    ITER_FULL(4,  bX) ITER_FULL(5,  bY) ITER_FULL(6,  bX) ITER_FULL(7,  bY)
    ITER_FULL(8,  bX) ITER_FULL(9,  bY) ITER_FULL(10, bX) ITER_FULL(11, bY)
    ITER_FULL(12, bX) ITER_FULL(13, bY) ITER_FULL(14, bX) ITER_FULL(15, bY)
    ITER_FULL(16, bX) ITER_FULL(17, bY) ITER_FULL(18, bX) ITER_FULL(19, bY)
    ITER_FULL(20, bX)
    ITER_NOS(21, bY)
    ITER_BARE(22, 8, bX)
    ITER_BARE(23, 0, bY)
#undef ITER_FULL
#undef ITER_NOS
#undef ITER_BARE
#undef ITER_BODY
#undef STAGE
#undef WAITVM
#undef SB

    // ---- epilogue: h = relu(acc + b1); logits = h @ W2 + b2; softmax; write
    float b1v[8], w2v[8][NCLS];
#pragma unroll
    for (int f = 0; f < 8; ++f) {
        int col = f * 16 + c0;
        b1v[f] = b1[col];
#pragma unroll
        for (int cc = 0; cc < NCLS; ++cc) w2v[f][cc] = W2[col * NCLS + cc];
    }
    float b2v[NCLS];
#pragma unroll
    for (int cc = 0; cc < NCLS; ++cc) b2v[cc] = b2[cc];

#pragma unroll
    for (int m = 0; m < 2; ++m) {
#pragma unroll
        for (int i = 0; i < 4; ++i) {
            float lg[NCLS] = {0.f, 0.f, 0.f, 0.f, 0.f};
#pragma unroll
            for (int f = 0; f < 8; ++f) {
                float h = acc[m][f][i] + b1v[f];
                h = fmaxf(h, 0.f);
#pragma unroll
                for (int cc = 0; cc < NCLS; ++cc) lg[cc] = fmaf(h, w2v[f][cc], lg[cc]);
            }
#pragma unroll
            for (int mask = 1; mask < 16; mask <<= 1) {
#pragma unroll
                for (int cc = 0; cc < NCLS; ++cc) lg[cc] += __shfl_xor(lg[cc], mask);
            }
#pragma unroll
            for (int cc = 0; cc < NCLS; ++cc) lg[cc] += b2v[cc];

            float mx = fmaxf(fmaxf(fmaxf(lg[0], lg[1]), fmaxf(lg[2], lg[3])), lg[4]);
            float q[NCLS];
            float s = 0.f;
#pragma unroll
            for (int cc = 0; cc < NCLS; ++cc) { q[cc] = __expf(lg[cc] - mx); s += q[cc]; }
            float inv = 1.0f / s;
            float num = (c0 == 0) ? q[0] : (c0 == 1) ? q[1] : (c0 == 2) ? q[2]
                      : (c0 == 3) ? q[3] : q[4];
            int eo = e0 + wv * 32 + m * 16 + g * 4 + i;
            if (eo < E_TOT && c0 < NCLS) out[(size_t)eo * NCLS + c0] = num * inv;
        }
    }
}

extern "C" void kernel_launch(void* const* d_in, const int* in_sizes, int n_in,
                              void* d_out, int out_size, void* d_ws, size_t ws_size,
                              hipStream_t stream) {
    const float* z    = (const float*)d_in[0];
    const int*   ei   = (const int*)d_in[1];
    const float* attr = (const float*)d_in[2];
    const float* W1   = (const float*)d_in[3];
    const float* b1   = (const float*)d_in[4];
    const float* W2   = (const float*)d_in[5];
    const float* b2   = (const float*)d_in[6];
    float* out = (float*)d_out;
    __hip_bfloat16* w1f = (__hip_bfloat16*)d_ws;   // 26*8*64*8*2 = 212992 B

    prep_w1f<<<(26 * 8 * 64 * 8 + 255) / 256, 256, 0, stream>>>(W1, w1f);
    const int nblk = (E_TOT + 127) / 128;   // 1563
    gcn_main<<<nblk, 256, 0, stream>>>(z, ei, attr, w1f, b1, W2, b2, out);
}